// Round 1
// 757.113 us; speedup vs baseline: 2.1000x; 2.1000x over previous
//
#include <hip/hip_runtime.h>
#include <stdint.h>

#define N_ROWS 65536
#define DIM    1000
#define KCB    256

// ---------------- old (proven) path: kept as fallback if ws_size is small ----------------
#define RB     64
#define DT     32
#define PITCH  36

__global__ __launch_bounds__(256) void wsq_old_kernel(const float* __restrict__ w,
                                                      float* __restrict__ wsq) {
    const int wave = threadIdx.x >> 6;
    const int lane = threadIdx.x & 63;
    const int k = blockIdx.x * 4 + wave;
    double s = 0.0;
    for (int c = lane; c < DIM / 4; c += 64) {
        const float4 v = *(const float4*)(w + k * DIM + c * 4);
        s += (double)v.x * v.x + (double)v.y * v.y + (double)v.z * v.z + (double)v.w * v.w;
    }
    #pragma unroll
    for (int off = 32; off; off >>= 1) s += __shfl_down(s, off, 64);
    if (lane == 0) wsq[k] = (float)s;
}

__global__ __launch_bounds__(256) void xsq_old_kernel(const float* __restrict__ x,
                                                      float* __restrict__ xsq) {
    const int wave = threadIdx.x >> 6;
    const int lane = threadIdx.x & 63;
    const int row = blockIdx.x * 4 + wave;
    double s = 0.0;
    for (int c = lane; c < DIM / 4; c += 64) {
        const float4 v = *(const float4*)(x + (size_t)row * DIM + c * 4);
        s += (double)v.x * v.x + (double)v.y * v.y + (double)v.z * v.z + (double)v.w * v.w;
    }
    #pragma unroll
    for (int off = 32; off; off >>= 1) s += __shfl_down(s, off, 64);
    if (lane == 0) xsq[row] = (float)s;
}

__global__ __launch_bounds__(256) void vq_old_kernel(const float* __restrict__ x,
                                                     const float* __restrict__ w,
                                                     const float* __restrict__ wsq,
                                                     const float* __restrict__ xsq,
                                                     float* __restrict__ out) {
    __shared__ float Xs[RB * PITCH];
    __shared__ float Ws[KCB * PITCH];
    __shared__ int   lidx[RB];

    const int tid  = threadIdx.x;
    const int row0 = blockIdx.x * RB;
    const int kt = tid & 31;
    const int rt = tid >> 5;

    double acc[8][8];
    #pragma unroll
    for (int i = 0; i < 8; i++)
        #pragma unroll
        for (int j = 0; j < 8; j++) acc[i][j] = 0.0;

    const int wk = tid >> 3;
    const int wg = tid & 7;
    const int xr = tid >> 2;
    const int xg = tid & 3;

    for (int d0 = 0; d0 < DIM; d0 += DT) {
        #pragma unroll
        for (int p = 0; p < 8; p++) {
            const int k = p * 32 + wk;
            const int d = d0 + wg * 4;
            float4 v = make_float4(0.f, 0.f, 0.f, 0.f);
            if (d < DIM) v = *(const float4*)(w + k * DIM + d);
            *(float4*)(&Ws[k * PITCH + wg * 4]) = v;
        }
        #pragma unroll
        for (int p = 0; p < 2; p++) {
            const int off = (xg + p * 4) * 4;
            const int d = d0 + off;
            float4 v = make_float4(0.f, 0.f, 0.f, 0.f);
            if (d < DIM) v = *(const float4*)(x + (size_t)(row0 + xr) * DIM + d);
            *(float4*)(&Xs[xr * PITCH + off]) = v;
        }
        __syncthreads();

        #pragma unroll
        for (int dq = 0; dq < DT; dq += 4) {
            float4 xf[8], wf[8];
            #pragma unroll
            for (int i = 0; i < 8; i++)
                xf[i] = *(const float4*)(&Xs[(rt + 8 * i) * PITCH + dq]);
            #pragma unroll
            for (int j = 0; j < 8; j++)
                wf[j] = *(const float4*)(&Ws[(kt + 32 * j) * PITCH + dq]);
            #pragma unroll
            for (int i = 0; i < 8; i++)
                #pragma unroll
                for (int j = 0; j < 8; j++) {
                    float p = xf[i].x * wf[j].x;
                    p = fmaf(xf[i].y, wf[j].y, p);
                    p = fmaf(xf[i].z, wf[j].z, p);
                    p = fmaf(xf[i].w, wf[j].w, p);
                    acc[i][j] += (double)p;
                }
        }
        __syncthreads();
    }

    #pragma unroll
    for (int i = 0; i < 8; i++) {
        const float xs = xsq[row0 + rt + 8 * i];
        float bestv = 3.4e38f;
        int   bestk = 0;
        #pragma unroll
        for (int j = 0; j < 8; j++) {
            const int k = kt + 32 * j;
            const float c32 = (float)acc[i][j];
            const float t1  = xs - 2.0f * c32;
            const float s   = t1 + wsq[k];
            if (s < bestv || (s == bestv && k < bestk)) { bestv = s; bestk = k; }
        }
        #pragma unroll
        for (int m = 16; m >= 1; m >>= 1) {
            const float ov = __shfl_xor(bestv, m, 64);
            const int   ok = __shfl_xor(bestk, m, 64);
            if (ov < bestv || (ov == bestv && ok < bestk)) { bestv = ov; bestk = ok; }
        }
        if (kt == 0) lidx[rt + 8 * i] = bestk;
    }
    __syncthreads();

    const int wave = tid >> 6;
    const int lane = tid & 63;
    for (int r = wave; r < RB; r += 4) {
        const int k = lidx[r];
        const float4* src = (const float4*)(w + k * DIM);
        float4* dst = (float4*)(out + (size_t)(row0 + r) * DIM);
        for (int c = lane; c < DIM / 4; c += 64) dst[c] = src[c];
    }
}

// ---------------- new MFMA path ----------------
// cross(n,k) approximated with 3 bf16 MFMA products (hi*Hi + hi*Lo + lo*Hi) in fp32.
// Guaranteed error bound -> candidate mask per row; exact fp64-quad recompute only for
// rows with >1 candidate. Output is bit-identical to the old pipeline.

#define RBM    64       // rows per block
#define NSTEP  32       // 1024 / 32 (D padded to 1024 with zeros)
#define XHI    0
#define XLO    4096
#define WHIO   8192
#define WLOO   24576
#define LDSB   40960    // bytes per buffer (X 8KB + W 32KB)

typedef short bf16x8 __attribute__((ext_vector_type(8)));
typedef float f32x4  __attribute__((ext_vector_type(4)));
typedef unsigned short us8 __attribute__((ext_vector_type(8)));

__device__ __forceinline__ unsigned short f2bf(float f) {  // RNE float->bf16
    union { float f; unsigned int u; } v; v.f = f;
    return (unsigned short)((v.u + 0x7FFFu + ((v.u >> 16) & 1u)) >> 16);
}
__device__ __forceinline__ float bf2f(unsigned short h) {
    union { float f; unsigned int u; } v; v.u = ((unsigned int)h) << 16;
    return v.f;
}
__device__ __forceinline__ void glds16(const void* g, void* l) {
    __builtin_amdgcn_global_load_lds((const __attribute__((address_space(1))) unsigned int*)g,
                                     (__attribute__((address_space(3))) unsigned int*)l, 16, 0, 0);
}

// wsq (bitwise-identical to old) + W split into fragment-arranged bf16 hi/lo arrays.
// Arranged layout: byte pos = step*16384 + ct*1024 + lane*16 + 2*j holds
// w[ct*16 + (lane&15)][32*step + 8*(lane>>4) + j]  -> main kernel stages W with pure glds16.
__global__ __launch_bounds__(256) void prep_kernel(const float* __restrict__ w,
        float* __restrict__ wsq, unsigned short* __restrict__ whi, unsigned short* __restrict__ wlo) {
    const int wave = threadIdx.x >> 6;
    const int lane = threadIdx.x & 63;
    const int k = blockIdx.x * 4 + wave;
    double s = 0.0;
    for (int c = lane; c < DIM / 4; c += 64) {
        const float4 v = *(const float4*)(w + k * DIM + c * 4);
        s += (double)v.x * v.x + (double)v.y * v.y + (double)v.z * v.z + (double)v.w * v.w;
    }
    #pragma unroll
    for (int off = 32; off; off >>= 1) s += __shfl_down(s, off, 64);
    if (lane == 0) wsq[k] = (float)s;

    const int ct = k >> 4, kl = k & 15;
    for (int c = lane; c < 256; c += 64) {           // 256 quads = 1024 padded dims
        float4 v = make_float4(0.f, 0.f, 0.f, 0.f);
        if (c < DIM / 4) v = *(const float4*)(w + k * DIM + c * 4);
        ushort4 h, l;
        h.x = f2bf(v.x); l.x = f2bf(v.x - bf2f(h.x));
        h.y = f2bf(v.y); l.y = f2bf(v.y - bf2f(h.y));
        h.z = f2bf(v.z); l.z = f2bf(v.z - bf2f(h.z));
        h.w = f2bf(v.w); l.w = f2bf(v.w - bf2f(h.w));
        const int step = c >> 3, qq = c & 7;
        const int pos = step * 16384 + ct * 1024 + ((qq >> 1) * 16 + kl) * 16 + (qq & 1) * 8;
        *(ushort4*)((char*)whi + pos) = h;
        *(ushort4*)((char*)wlo + pos) = l;
    }
}

// xsq bitwise-identical to old + S1 = sum|x| (fp64) for the margin bound.
__global__ __launch_bounds__(256) void xsq_s1_kernel(const float* __restrict__ x,
        float* __restrict__ xsq, float* __restrict__ s1) {
    const int wave = threadIdx.x >> 6;
    const int lane = threadIdx.x & 63;
    const int row = blockIdx.x * 4 + wave;
    double s = 0.0, a = 0.0;
    for (int c = lane; c < DIM / 4; c += 64) {
        const float4 v = *(const float4*)(x + (size_t)row * DIM + c * 4);
        s += (double)v.x * v.x + (double)v.y * v.y + (double)v.z * v.z + (double)v.w * v.w;
        a += (double)fabsf(v.x) + (double)fabsf(v.y) + (double)fabsf(v.z) + (double)fabsf(v.w);
    }
    #pragma unroll
    for (int off = 32; off; off >>= 1) { s += __shfl_down(s, off, 64); a += __shfl_down(a, off, 64); }
    if (lane == 0) { xsq[row] = (float)s; s1[row] = (float)a; }
}

__global__ __launch_bounds__(256, 2) void vq_main_kernel(
        const float* __restrict__ x, const float* __restrict__ w,
        const float* __restrict__ wsq, const float* __restrict__ xsq,
        const float* __restrict__ s1,
        const unsigned short* __restrict__ whi, const unsigned short* __restrict__ wlo,
        unsigned int* __restrict__ cmask, float* __restrict__ out) {
    __shared__ __align__(16) char lds[2 * LDSB];   // 80 KB -> 2 blocks/CU
    const int tid  = threadIdx.x;
    const int lane = tid & 63;
    const int wv   = tid >> 6;          // code group: codes [64*wv, 64*wv+64)
    const int row0 = blockIdx.x * RBM;

    // X staging: thread -> row = tid>>2, even quad pair sq0 = (tid&3)*2 (its 2 quads land
    // in one contiguous 16B fragment slot -> single b128 write per term)
    const int srow = tid >> 2;
    const int sq0  = (tid & 3) * 2;
    const size_t xrow_off = (size_t)(row0 + srow) * DIM;
    const int xpos0 = (srow >> 4) * 1024 + ((sq0 >> 1) * 16 + (srow & 15)) * 16;

    f32x4 acc[4][4];
    {
        const f32x4 z = {0.f, 0.f, 0.f, 0.f};
        #pragma unroll
        for (int i = 0; i < 4; i++)
            #pragma unroll
            for (int j = 0; j < 4; j++) acc[i][j] = z;
    }

    float4 xa, xb;
    auto xload = [&](int t) {
        const int dA = t * 32 + sq0 * 4, dB = dA + 4;
        xa = (dA <= DIM - 4) ? *(const float4*)(x + xrow_off + dA) : make_float4(0.f, 0.f, 0.f, 0.f);
        xb = (dB <= DIM - 4) ? *(const float4*)(x + xrow_off + dB) : make_float4(0.f, 0.f, 0.f, 0.f);
    };
    auto xwrite = [&](int b) {
        us8 h, l;
        h[0] = f2bf(xa.x); l[0] = f2bf(xa.x - bf2f(h[0]));
        h[1] = f2bf(xa.y); l[1] = f2bf(xa.y - bf2f(h[1]));
        h[2] = f2bf(xa.z); l[2] = f2bf(xa.z - bf2f(h[2]));
        h[3] = f2bf(xa.w); l[3] = f2bf(xa.w - bf2f(h[3]));
        h[4] = f2bf(xb.x); l[4] = f2bf(xb.x - bf2f(h[4]));
        h[5] = f2bf(xb.y); l[5] = f2bf(xb.y - bf2f(h[5]));
        h[6] = f2bf(xb.z); l[6] = f2bf(xb.z - bf2f(h[6]));
        h[7] = f2bf(xb.w); l[7] = f2bf(xb.w - bf2f(h[7]));
        *(us8*)(lds + b * LDSB + XHI + xpos0) = h;
        *(us8*)(lds + b * LDSB + XLO + xpos0) = l;
    };
    auto wstage = [&](int b, int t) {
        #pragma unroll
        for (int i = 0; i < 4; i++) {
            const int ch = wv * 4 + i;
            glds16(whi + (size_t)t * 8192 + ch * 512 + lane * 8, lds + b * LDSB + WHIO + ch * 1024);
            glds16(wlo + (size_t)t * 8192 + ch * 512 + lane * 8, lds + b * LDSB + WLOO + ch * 1024);
        }
    };
    auto compute = [&](int b) {
        const char* base = lds + b * LDSB;
        bf16x8 ahi[4], alo[4];
        #pragma unroll
        for (int rt = 0; rt < 4; rt++) {
            ahi[rt] = *(const bf16x8*)(base + XHI + rt * 1024 + lane * 16);
            alo[rt] = *(const bf16x8*)(base + XLO + rt * 1024 + lane * 16);
        }
        #pragma unroll
        for (int jt = 0; jt < 4; jt++) {
            const int ct = wv * 4 + jt;
            const bf16x8 bhi = *(const bf16x8*)(base + WHIO + ct * 1024 + lane * 16);
            const bf16x8 blo = *(const bf16x8*)(base + WLOO + ct * 1024 + lane * 16);
            #pragma unroll
            for (int rt = 0; rt < 4; rt++) {
                acc[rt][jt] = __builtin_amdgcn_mfma_f32_16x16x32_bf16(ahi[rt], bhi, acc[rt][jt], 0, 0, 0);
                acc[rt][jt] = __builtin_amdgcn_mfma_f32_16x16x32_bf16(ahi[rt], blo, acc[rt][jt], 0, 0, 0);
                acc[rt][jt] = __builtin_amdgcn_mfma_f32_16x16x32_bf16(alo[rt], bhi, acc[rt][jt], 0, 0, 0);
            }
        }
    };

    // prologue + double-buffered main loop
    xload(0); wstage(0, 0); xwrite(0);
    __syncthreads();
    for (int t = 0; t < NSTEP; t++) {
        const int cur = t & 1;
        if (t + 1 < NSTEP) { xload(t + 1); wstage(1 - cur, t + 1); }
        compute(cur);
        if (t + 1 < NSTEP) xwrite(1 - cur);
        __syncthreads();
    }

    // ---- epilogue: shat, per-row min, margin mask ----
    const int g  = lane >> 4;
    const int cl = lane & 15;
    float* minw = (float*)lds;                           // [64][4]
    unsigned short* m16 = (unsigned short*)(lds + 1024); // [64][16]
    int* lidx = (int*)(lds + 3072);                      // [64]

    float wsqv[4];
    #pragma unroll
    for (int jt = 0; jt < 4; jt++) wsqv[jt] = wsq[wv * 64 + jt * 16 + cl];

    float xsv[4][4], mv[4][4];
    #pragma unroll
    for (int rt = 0; rt < 4; rt++)
        #pragma unroll
        for (int e = 0; e < 4; e++) {
            const int r = row0 + rt * 16 + g * 4 + e;
            const float xs = xsq[r];
            xsv[rt][e] = xs;
            // guaranteed margin: 4*(split 1.81e-7 + mfma-accum 7.6e-7)*S1 + 4ulp(~xs) (+headroom)
            mv[rt][e] = 6e-6f * s1[r] + 8e-7f * (xs + 1.0f) + 1e-12f;
        }

    #pragma unroll
    for (int rt = 0; rt < 4; rt++)
        #pragma unroll
        for (int jt = 0; jt < 4; jt++)
            #pragma unroll
            for (int e = 0; e < 4; e++) {
                const float c = acc[rt][jt][e];
                const float t1 = xsv[rt][e] - 2.0f * c;
                acc[rt][jt][e] = t1 + wsqv[jt];      // shat, same rounding pipeline as exact path
            }

    #pragma unroll
    for (int rt = 0; rt < 4; rt++)
        #pragma unroll
        for (int e = 0; e < 4; e++) {
            float mn = fminf(fminf(acc[rt][0][e], acc[rt][1][e]), fminf(acc[rt][2][e], acc[rt][3][e]));
            #pragma unroll
            for (int m = 8; m; m >>= 1) mn = fminf(mn, __shfl_xor(mn, m, 64));
            if (cl == 0) minw[(rt * 16 + g * 4 + e) * 4 + wv] = mn;
        }
    __syncthreads();

    float tv[4][4];
    #pragma unroll
    for (int rt = 0; rt < 4; rt++)
        #pragma unroll
        for (int e = 0; e < 4; e++) {
            const int r = rt * 16 + g * 4 + e;
            const float gm = fminf(fminf(minw[r * 4 + 0], minw[r * 4 + 1]),
                                   fminf(minw[r * 4 + 2], minw[r * 4 + 3]));
            tv[rt][e] = gm + mv[rt][e];
        }
    #pragma unroll
    for (int rt = 0; rt < 4; rt++)
        #pragma unroll
        for (int jt = 0; jt < 4; jt++)
            #pragma unroll
            for (int e = 0; e < 4; e++) {
                const unsigned long long b = __ballot(acc[rt][jt][e] <= tv[rt][e]);
                if (cl == 0)
                    m16[(rt * 16 + g * 4 + e) * 16 + wv * 4 + jt] = (unsigned short)(b >> (g * 16));
            }
    __syncthreads();

    if (wv == 0) {
        unsigned int mw[8];
        #pragma unroll
        for (int i = 0; i < 8; i++)
            mw[i] = (unsigned int)m16[lane * 16 + 2 * i] | ((unsigned int)m16[lane * 16 + 2 * i + 1] << 16);
        int kb = 0;
        #pragma unroll
        for (int i = 7; i >= 0; i--) if (mw[i]) kb = 32 * i + __ffs(mw[i]) - 1;   // lowest set bit
        lidx[lane] = kb;
        unsigned int* mrow = cmask + (size_t)(row0 + lane) * 8;
        #pragma unroll
        for (int i = 0; i < 8; i++) mrow[i] = mw[i];
    }
    __syncthreads();

    for (int r = wv; r < RBM; r += 4) {
        const int k = lidx[r];
        const float4* src = (const float4*)(w + (size_t)k * DIM);
        float4* dst = (float4*)(out + (size_t)(row0 + r) * DIM);
        for (int c = lane; c < DIM / 4; c += 64) dst[c] = src[c];
    }
}

// Exact fp64-quad recompute for rows with >1 candidate; rewrites the output row.
__global__ __launch_bounds__(256) void resolve_kernel(const float* __restrict__ x,
        const float* __restrict__ w, const float* __restrict__ wsq,
        const float* __restrict__ xsq, const unsigned int* __restrict__ cmask,
        float* __restrict__ out) {
    const int wave = threadIdx.x >> 6;
    const int lane = threadIdx.x & 63;
    const int row = blockIdx.x * 4 + wave;
    unsigned int mw[8];
    int cnt = 0;
    #pragma unroll
    for (int i = 0; i < 8; i++) { mw[i] = cmask[(size_t)row * 8 + i]; cnt += __popc(mw[i]); }
    if (cnt <= 1) return;

    float4 xq[4];
    #pragma unroll
    for (int p = 0; p < 4; p++) {
        const int c = lane + 64 * p;
        xq[p] = (c < DIM / 4) ? *(const float4*)(x + (size_t)row * DIM + c * 4)
                              : make_float4(0.f, 0.f, 0.f, 0.f);
    }
    const float xs = xsq[row];
    float bv = 3.4e38f; int bk = KCB;
    for (int k = 0; k < KCB; k++) {
        if (!((mw[k >> 5] >> (k & 31)) & 1u)) continue;
        double a = 0.0;
        #pragma unroll
        for (int p = 0; p < 4; p++) {
            const int c = lane + 64 * p;
            if (c < DIM / 4) {
                const float4 wq = *(const float4*)(w + (size_t)k * DIM + c * 4);
                float pt = xq[p].x * wq.x;
                pt = fmaf(xq[p].y, wq.y, pt);
                pt = fmaf(xq[p].z, wq.z, pt);
                pt = fmaf(xq[p].w, wq.w, pt);
                a += (double)pt;
            }
        }
        #pragma unroll
        for (int off = 32; off; off >>= 1) a += __shfl_xor(a, off, 64);
        const float c32 = (float)a;
        const float t1 = xs - 2.0f * c32;
        const float sv = t1 + wsq[k];
        if (sv < bv) { bv = sv; bk = k; }    // ascending k + strict < == lowest-index tiebreak
    }
    const float4* src = (const float4*)(w + (size_t)bk * DIM);
    float4* dst = (float4*)(out + (size_t)row * DIM);
    for (int c = lane; c < DIM / 4; c += 64) dst[c] = src[c];
}

extern "C" void kernel_launch(void* const* d_in, const int* in_sizes, int n_in,
                              void* d_out, int out_size, void* d_ws, size_t ws_size,
                              hipStream_t stream) {
    const float* x = (const float*)d_in[0];
    const float* w = (const float*)d_in[1];
    float* out  = (float*)d_out;
    float* base = (float*)d_ws;

    // workspace words: wsq 256 | xsq 65536 | s1 65536 | cmask 524288 | whi 131072 | wlo 131072
    const size_t NEED = 917760ull * 4ull;
    if (ws_size < NEED) {   // fallback: proven old path (needs only 257 KB)
        float* wsq = base;
        float* xsq = wsq + KCB;
        wsq_old_kernel<<<KCB / 4, 256, 0, stream>>>(w, wsq);
        xsq_old_kernel<<<N_ROWS / 4, 256, 0, stream>>>(x, xsq);
        vq_old_kernel<<<N_ROWS / RB, 256, 0, stream>>>(x, w, wsq, xsq, out);
        return;
    }

    float* wsq = base;                                      // 256
    float* xsq = base + 256;                                // 65536
    float* s1  = base + 65792;                              // 65536
    unsigned int*   cmask = (unsigned int*)(base + 131328); // 524288
    unsigned short* whi   = (unsigned short*)(base + 655616);
    unsigned short* wlo   = (unsigned short*)(base + 786688);

    prep_kernel<<<KCB / 4, 256, 0, stream>>>(w, wsq, whi, wlo);
    xsq_s1_kernel<<<N_ROWS / 4, 256, 0, stream>>>(x, xsq, s1);
    vq_main_kernel<<<N_ROWS / RBM, 256, 0, stream>>>(x, w, wsq, xsq, s1, whi, wlo, cmask, out);
    resolve_kernel<<<N_ROWS / 4, 256, 0, stream>>>(x, w, wsq, xsq, cmask, out);
}

// Round 2
// 590.304 us; speedup vs baseline: 2.6934x; 1.2826x over previous
//
#include <hip/hip_runtime.h>
#include <stdint.h>

#define N_ROWS 65536
#define DIM    1000
#define KCB    256

// ---------------- old (proven) path: kept as fallback if ws_size is small ----------------
#define RB     64
#define DT     32
#define PITCH  36

__global__ __launch_bounds__(256) void wsq_old_kernel(const float* __restrict__ w,
                                                      float* __restrict__ wsq) {
    const int wave = threadIdx.x >> 6;
    const int lane = threadIdx.x & 63;
    const int k = blockIdx.x * 4 + wave;
    double s = 0.0;
    for (int c = lane; c < DIM / 4; c += 64) {
        const float4 v = *(const float4*)(w + k * DIM + c * 4);
        s += (double)v.x * v.x + (double)v.y * v.y + (double)v.z * v.z + (double)v.w * v.w;
    }
    #pragma unroll
    for (int off = 32; off; off >>= 1) s += __shfl_down(s, off, 64);
    if (lane == 0) wsq[k] = (float)s;
}

__global__ __launch_bounds__(256) void xsq_old_kernel(const float* __restrict__ x,
                                                      float* __restrict__ xsq) {
    const int wave = threadIdx.x >> 6;
    const int lane = threadIdx.x & 63;
    const int row = blockIdx.x * 4 + wave;
    double s = 0.0;
    for (int c = lane; c < DIM / 4; c += 64) {
        const float4 v = *(const float4*)(x + (size_t)row * DIM + c * 4);
        s += (double)v.x * v.x + (double)v.y * v.y + (double)v.z * v.z + (double)v.w * v.w;
    }
    #pragma unroll
    for (int off = 32; off; off >>= 1) s += __shfl_down(s, off, 64);
    if (lane == 0) xsq[row] = (float)s;
}

__global__ __launch_bounds__(256) void vq_old_kernel(const float* __restrict__ x,
                                                     const float* __restrict__ w,
                                                     const float* __restrict__ wsq,
                                                     const float* __restrict__ xsq,
                                                     float* __restrict__ out) {
    __shared__ float Xs[RB * PITCH];
    __shared__ float Ws[KCB * PITCH];
    __shared__ int   lidx[RB];

    const int tid  = threadIdx.x;
    const int row0 = blockIdx.x * RB;
    const int kt = tid & 31;
    const int rt = tid >> 5;

    double acc[8][8];
    #pragma unroll
    for (int i = 0; i < 8; i++)
        #pragma unroll
        for (int j = 0; j < 8; j++) acc[i][j] = 0.0;

    const int wk = tid >> 3;
    const int wg = tid & 7;
    const int xr = tid >> 2;
    const int xg = tid & 3;

    for (int d0 = 0; d0 < DIM; d0 += DT) {
        #pragma unroll
        for (int p = 0; p < 8; p++) {
            const int k = p * 32 + wk;
            const int d = d0 + wg * 4;
            float4 v = make_float4(0.f, 0.f, 0.f, 0.f);
            if (d < DIM) v = *(const float4*)(w + k * DIM + d);
            *(float4*)(&Ws[k * PITCH + wg * 4]) = v;
        }
        #pragma unroll
        for (int p = 0; p < 2; p++) {
            const int off = (xg + p * 4) * 4;
            const int d = d0 + off;
            float4 v = make_float4(0.f, 0.f, 0.f, 0.f);
            if (d < DIM) v = *(const float4*)(x + (size_t)(row0 + xr) * DIM + d);
            *(float4*)(&Xs[xr * PITCH + off]) = v;
        }
        __syncthreads();

        #pragma unroll
        for (int dq = 0; dq < DT; dq += 4) {
            float4 xf[8], wf[8];
            #pragma unroll
            for (int i = 0; i < 8; i++)
                xf[i] = *(const float4*)(&Xs[(rt + 8 * i) * PITCH + dq]);
            #pragma unroll
            for (int j = 0; j < 8; j++)
                wf[j] = *(const float4*)(&Ws[(kt + 32 * j) * PITCH + dq]);
            #pragma unroll
            for (int i = 0; i < 8; i++)
                #pragma unroll
                for (int j = 0; j < 8; j++) {
                    float p = xf[i].x * wf[j].x;
                    p = fmaf(xf[i].y, wf[j].y, p);
                    p = fmaf(xf[i].z, wf[j].z, p);
                    p = fmaf(xf[i].w, wf[j].w, p);
                    acc[i][j] += (double)p;
                }
        }
        __syncthreads();
    }

    #pragma unroll
    for (int i = 0; i < 8; i++) {
        const float xs = xsq[row0 + rt + 8 * i];
        float bestv = 3.4e38f;
        int   bestk = 0;
        #pragma unroll
        for (int j = 0; j < 8; j++) {
            const int k = kt + 32 * j;
            const float c32 = (float)acc[i][j];
            const float t1  = xs - 2.0f * c32;
            const float s   = t1 + wsq[k];
            if (s < bestv || (s == bestv && k < bestk)) { bestv = s; bestk = k; }
        }
        #pragma unroll
        for (int m = 16; m >= 1; m >>= 1) {
            const float ov = __shfl_xor(bestv, m, 64);
            const int   ok = __shfl_xor(bestk, m, 64);
            if (ov < bestv || (ov == bestv && ok < bestk)) { bestv = ov; bestk = ok; }
        }
        if (kt == 0) lidx[rt + 8 * i] = bestk;
    }
    __syncthreads();

    const int wave = tid >> 6;
    const int lane = tid & 63;
    for (int r = wave; r < RB; r += 4) {
        const int k = lidx[r];
        const float4* src = (const float4*)(w + k * DIM);
        float4* dst = (float4*)(out + (size_t)(row0 + r) * DIM);
        for (int c = lane; c < DIM / 4; c += 64) dst[c] = src[c];
    }
}

// ---------------- MFMA path ----------------
// cross(n,k) approximated with 3 bf16 MFMA products in fp32 with SPLIT accumulators:
//   acc_m: hi*Hi (32-deep chain at full magnitude P)
//   acc_c: hi*Lo + lo*Hi (64-deep chain at 2^-9 * P magnitude)
// Rigorous error (|w| <= 2^-8 by construction, P = sum|x||w| <= 2^-8 * S1):
//   split/ideal <= 1.3e-5*P; acc_m (RTZ-pessimistic) <= 2048*eps*P; acc_c negligible
//   -> |c_hat - c| <= 5.4e-7*S1; margin M = 2E = 2*(2*dc + pipeline ulps)
//   -> M = 2.5e-6*S1 + 6e-7*(xs+64) covers with >=2x headroom.
// Rows with >1 candidate within M are appended to a compact list; resolve_kernel
// re-runs the exact fp64-quad pipeline only for those (grid-stride over list).

#define RBM    64       // rows per block
#define NSTEP  32       // 1024 / 32 (D padded to 1024 with zeros)
#define XHI    0
#define XLO    4096
#define WHIO   8192
#define WLOO   24576
#define LDSB   40960    // bytes per buffer (X 8KB + W 32KB)

typedef short bf16x8 __attribute__((ext_vector_type(8)));
typedef float f32x4  __attribute__((ext_vector_type(4)));
typedef unsigned short us8 __attribute__((ext_vector_type(8)));

__device__ __forceinline__ unsigned short f2bf(float f) {  // RNE float->bf16
    union { float f; unsigned int u; } v; v.f = f;
    return (unsigned short)((v.u + 0x7FFFu + ((v.u >> 16) & 1u)) >> 16);
}
__device__ __forceinline__ float bf2f(unsigned short h) {
    union { float f; unsigned int u; } v; v.u = ((unsigned int)h) << 16;
    return v.f;
}
__device__ __forceinline__ void glds16(const void* g, void* l) {
    __builtin_amdgcn_global_load_lds((const __attribute__((address_space(1))) unsigned int*)g,
                                     (__attribute__((address_space(3))) unsigned int*)l, 16, 0, 0);
}

// wsq (bitwise-identical to old) + W split into fragment-arranged bf16 hi/lo arrays.
// Also zeroes the resolve-list counter (prep is the first kernel in the stream).
__global__ __launch_bounds__(256) void prep_kernel(const float* __restrict__ w,
        float* __restrict__ wsq, unsigned short* __restrict__ whi, unsigned short* __restrict__ wlo,
        unsigned int* __restrict__ counter) {
    if (blockIdx.x == 0 && threadIdx.x == 0) counter[0] = 0;
    const int wave = threadIdx.x >> 6;
    const int lane = threadIdx.x & 63;
    const int k = blockIdx.x * 4 + wave;
    double s = 0.0;
    for (int c = lane; c < DIM / 4; c += 64) {
        const float4 v = *(const float4*)(w + k * DIM + c * 4);
        s += (double)v.x * v.x + (double)v.y * v.y + (double)v.z * v.z + (double)v.w * v.w;
    }
    #pragma unroll
    for (int off = 32; off; off >>= 1) s += __shfl_down(s, off, 64);
    if (lane == 0) wsq[k] = (float)s;

    const int ct = k >> 4, kl = k & 15;
    for (int c = lane; c < 256; c += 64) {           // 256 quads = 1024 padded dims
        float4 v = make_float4(0.f, 0.f, 0.f, 0.f);
        if (c < DIM / 4) v = *(const float4*)(w + k * DIM + c * 4);
        ushort4 h, l;
        h.x = f2bf(v.x); l.x = f2bf(v.x - bf2f(h.x));
        h.y = f2bf(v.y); l.y = f2bf(v.y - bf2f(h.y));
        h.z = f2bf(v.z); l.z = f2bf(v.z - bf2f(h.z));
        h.w = f2bf(v.w); l.w = f2bf(v.w - bf2f(h.w));
        const int step = c >> 3, qq = c & 7;
        const int pos = step * 16384 + ct * 1024 + ((qq >> 1) * 16 + kl) * 16 + (qq & 1) * 8;
        *(ushort4*)((char*)whi + pos) = h;
        *(ushort4*)((char*)wlo + pos) = l;
    }
}

// xsq bitwise-identical to old + S1 = sum|x| (fp64) for the margin bound.
__global__ __launch_bounds__(256) void xsq_s1_kernel(const float* __restrict__ x,
        float* __restrict__ xsq, float* __restrict__ s1) {
    const int wave = threadIdx.x >> 6;
    const int lane = threadIdx.x & 63;
    const int row = blockIdx.x * 4 + wave;
    double s = 0.0, a = 0.0;
    for (int c = lane; c < DIM / 4; c += 64) {
        const float4 v = *(const float4*)(x + (size_t)row * DIM + c * 4);
        s += (double)v.x * v.x + (double)v.y * v.y + (double)v.z * v.z + (double)v.w * v.w;
        a += (double)fabsf(v.x) + (double)fabsf(v.y) + (double)fabsf(v.z) + (double)fabsf(v.w);
    }
    #pragma unroll
    for (int off = 32; off; off >>= 1) { s += __shfl_down(s, off, 64); a += __shfl_down(a, off, 64); }
    if (lane == 0) { xsq[row] = (float)s; s1[row] = (float)a; }
}

__global__ __launch_bounds__(256, 2) void vq_main_kernel(
        const float* __restrict__ x, const float* __restrict__ w,
        const float* __restrict__ wsq, const float* __restrict__ xsq,
        const float* __restrict__ s1,
        const unsigned short* __restrict__ whi, const unsigned short* __restrict__ wlo,
        unsigned int* __restrict__ cmask, unsigned int* __restrict__ rlist,
        unsigned int* __restrict__ counter, float* __restrict__ out) {
    __shared__ __align__(16) char lds[2 * LDSB];   // 80 KB -> 2 blocks/CU
    const int tid  = threadIdx.x;
    const int lane = tid & 63;
    const int wv   = tid >> 6;          // code group: codes [64*wv, 64*wv+64)
    const int row0 = blockIdx.x * RBM;

    const int srow = tid >> 2;
    const int sq0  = (tid & 3) * 2;
    const size_t xrow_off = (size_t)(row0 + srow) * DIM;
    const int xpos0 = (srow >> 4) * 1024 + ((sq0 >> 1) * 16 + (srow & 15)) * 16;

    f32x4 accm[4][4], accc[4][4];
    {
        const f32x4 z = {0.f, 0.f, 0.f, 0.f};
        #pragma unroll
        for (int i = 0; i < 4; i++)
            #pragma unroll
            for (int j = 0; j < 4; j++) { accm[i][j] = z; accc[i][j] = z; }
    }

    float4 xa, xb;
    auto xload = [&](int t) {
        const int dA = t * 32 + sq0 * 4, dB = dA + 4;
        xa = (dA <= DIM - 4) ? *(const float4*)(x + xrow_off + dA) : make_float4(0.f, 0.f, 0.f, 0.f);
        xb = (dB <= DIM - 4) ? *(const float4*)(x + xrow_off + dB) : make_float4(0.f, 0.f, 0.f, 0.f);
    };
    auto xwrite = [&](int b) {
        us8 h, l;
        h[0] = f2bf(xa.x); l[0] = f2bf(xa.x - bf2f(h[0]));
        h[1] = f2bf(xa.y); l[1] = f2bf(xa.y - bf2f(h[1]));
        h[2] = f2bf(xa.z); l[2] = f2bf(xa.z - bf2f(h[2]));
        h[3] = f2bf(xa.w); l[3] = f2bf(xa.w - bf2f(h[3]));
        h[4] = f2bf(xb.x); l[4] = f2bf(xb.x - bf2f(h[4]));
        h[5] = f2bf(xb.y); l[5] = f2bf(xb.y - bf2f(h[5]));
        h[6] = f2bf(xb.z); l[6] = f2bf(xb.z - bf2f(h[6]));
        h[7] = f2bf(xb.w); l[7] = f2bf(xb.w - bf2f(h[7]));
        *(us8*)(lds + b * LDSB + XHI + xpos0) = h;
        *(us8*)(lds + b * LDSB + XLO + xpos0) = l;
    };
    auto wstage = [&](int b, int t) {
        #pragma unroll
        for (int i = 0; i < 4; i++) {
            const int ch = wv * 4 + i;
            glds16(whi + (size_t)t * 8192 + ch * 512 + lane * 8, lds + b * LDSB + WHIO + ch * 1024);
            glds16(wlo + (size_t)t * 8192 + ch * 512 + lane * 8, lds + b * LDSB + WLOO + ch * 1024);
        }
    };
    auto compute = [&](int b) {
        const char* base = lds + b * LDSB;
        bf16x8 ahi[4], alo[4];
        #pragma unroll
        for (int rt = 0; rt < 4; rt++) {
            ahi[rt] = *(const bf16x8*)(base + XHI + rt * 1024 + lane * 16);
            alo[rt] = *(const bf16x8*)(base + XLO + rt * 1024 + lane * 16);
        }
        __builtin_amdgcn_s_setprio(1);
        #pragma unroll
        for (int jt = 0; jt < 4; jt++) {
            const int ct = wv * 4 + jt;
            const bf16x8 bhi = *(const bf16x8*)(base + WHIO + ct * 1024 + lane * 16);
            const bf16x8 blo = *(const bf16x8*)(base + WLOO + ct * 1024 + lane * 16);
            #pragma unroll
            for (int rt = 0; rt < 4; rt++) {
                accm[rt][jt] = __builtin_amdgcn_mfma_f32_16x16x32_bf16(ahi[rt], bhi, accm[rt][jt], 0, 0, 0);
                accc[rt][jt] = __builtin_amdgcn_mfma_f32_16x16x32_bf16(ahi[rt], blo, accc[rt][jt], 0, 0, 0);
                accc[rt][jt] = __builtin_amdgcn_mfma_f32_16x16x32_bf16(alo[rt], bhi, accc[rt][jt], 0, 0, 0);
            }
        }
        __builtin_amdgcn_s_setprio(0);
    };

    // prologue + double-buffered main loop
    xload(0); wstage(0, 0); xwrite(0);
    __syncthreads();
    for (int t = 0; t < NSTEP; t++) {
        const int cur = t & 1;
        if (t + 1 < NSTEP) { xload(t + 1); wstage(1 - cur, t + 1); }
        compute(cur);
        if (t + 1 < NSTEP) xwrite(1 - cur);
        __syncthreads();
    }

    // merge split accumulators: c_hat = acc_m + acc_c (one fp32 rounding, in margin budget)
    #pragma unroll
    for (int i = 0; i < 4; i++)
        #pragma unroll
        for (int j = 0; j < 4; j++) accm[i][j] += accc[i][j];

    // ---- epilogue: shat, per-row min, margin mask ----
    const int g  = lane >> 4;
    const int cl = lane & 15;
    float* minw = (float*)lds;                           // [64][4]
    unsigned short* m16 = (unsigned short*)(lds + 1024); // [64][16]
    int* lidx = (int*)(lds + 3072);                      // [64]

    float wsqv[4];
    #pragma unroll
    for (int jt = 0; jt < 4; jt++) wsqv[jt] = wsq[wv * 64 + jt * 16 + cl];

    float xsv[4][4], mv[4][4];
    #pragma unroll
    for (int rt = 0; rt < 4; rt++)
        #pragma unroll
        for (int e = 0; e < 4; e++) {
            const int r = row0 + rt * 16 + g * 4 + e;
            const float xs = xsq[r];
            xsv[rt][e] = xs;
            // split-accumulator margin (see header comment): >=2x headroom everywhere
            mv[rt][e] = 2.5e-6f * s1[r] + 6e-7f * (xs + 64.0f) + 1e-12f;
        }

    #pragma unroll
    for (int rt = 0; rt < 4; rt++)
        #pragma unroll
        for (int jt = 0; jt < 4; jt++)
            #pragma unroll
            for (int e = 0; e < 4; e++) {
                const float c = accm[rt][jt][e];
                const float t1 = xsv[rt][e] - 2.0f * c;
                accm[rt][jt][e] = t1 + wsqv[jt];      // shat, same rounding pipeline as exact path
            }

    #pragma unroll
    for (int rt = 0; rt < 4; rt++)
        #pragma unroll
        for (int e = 0; e < 4; e++) {
            float mn = fminf(fminf(accm[rt][0][e], accm[rt][1][e]), fminf(accm[rt][2][e], accm[rt][3][e]));
            #pragma unroll
            for (int m = 8; m; m >>= 1) mn = fminf(mn, __shfl_xor(mn, m, 64));
            if (cl == 0) minw[(rt * 16 + g * 4 + e) * 4 + wv] = mn;
        }
    __syncthreads();

    float tv[4][4];
    #pragma unroll
    for (int rt = 0; rt < 4; rt++)
        #pragma unroll
        for (int e = 0; e < 4; e++) {
            const int r = rt * 16 + g * 4 + e;
            const float gm = fminf(fminf(minw[r * 4 + 0], minw[r * 4 + 1]),
                                   fminf(minw[r * 4 + 2], minw[r * 4 + 3]));
            tv[rt][e] = gm + mv[rt][e];
        }
    #pragma unroll
    for (int rt = 0; rt < 4; rt++)
        #pragma unroll
        for (int jt = 0; jt < 4; jt++)
            #pragma unroll
            for (int e = 0; e < 4; e++) {
                const unsigned long long b = __ballot(accm[rt][jt][e] <= tv[rt][e]);
                if (cl == 0)
                    m16[(rt * 16 + g * 4 + e) * 16 + wv * 4 + jt] = (unsigned short)(b >> (g * 16));
            }
    __syncthreads();

    if (wv == 0) {
        unsigned int mw[8];
        int cnt = 0;
        #pragma unroll
        for (int i = 0; i < 8; i++) {
            mw[i] = (unsigned int)m16[lane * 16 + 2 * i] | ((unsigned int)m16[lane * 16 + 2 * i + 1] << 16);
            cnt += __popc(mw[i]);
        }
        int kb = 0;
        #pragma unroll
        for (int i = 7; i >= 0; i--) if (mw[i]) kb = 32 * i + __ffs(mw[i]) - 1;   // lowest set bit
        lidx[lane] = kb;
        unsigned int* mrow = cmask + (size_t)(row0 + lane) * 8;
        #pragma unroll
        for (int i = 0; i < 8; i++) mrow[i] = mw[i];

        // append multi-candidate rows to the compact resolve list (one atomic per wave)
        const unsigned long long act = __ballot(cnt > 1);
        const int tot = __popcll(act);
        unsigned int basep = 0;
        if (lane == 0 && tot > 0) basep = atomicAdd(counter, (unsigned int)tot);
        basep = __shfl(basep, 0, 64);
        if (cnt > 1) {
            const int pfx = __popcll(act & ((1ull << lane) - 1ull));
            rlist[basep + pfx] = (unsigned int)(row0 + lane);
        }
    }
    __syncthreads();

    for (int r = wv; r < RBM; r += 4) {
        const int k = lidx[r];
        const float4* src = (const float4*)(w + (size_t)k * DIM);
        float4* dst = (float4*)(out + (size_t)(row0 + r) * DIM);
        for (int c = lane; c < DIM / 4; c += 64) dst[c] = src[c];
    }
}

// Exact fp64-quad recompute, grid-stride over the COMPACTED multi-candidate row list.
__global__ __launch_bounds__(256) void resolve_kernel(const float* __restrict__ x,
        const float* __restrict__ w, const float* __restrict__ wsq,
        const float* __restrict__ xsq, const unsigned int* __restrict__ cmask,
        const unsigned int* __restrict__ rlist, const unsigned int* __restrict__ counter,
        float* __restrict__ out) {
    const int nact = (int)counter[0];
    const int wv   = threadIdx.x >> 6;
    const int lane = threadIdx.x & 63;
    const int nw   = gridDim.x * 4;

    for (int i = blockIdx.x * 4 + wv; i < nact; i += nw) {
        const int row = (int)rlist[i];
        unsigned int mw[8];
        #pragma unroll
        for (int q = 0; q < 8; q++) mw[q] = cmask[(size_t)row * 8 + q];

        float4 xq[4];
        #pragma unroll
        for (int p = 0; p < 4; p++) {
            const int c = lane + 64 * p;
            xq[p] = (c < DIM / 4) ? *(const float4*)(x + (size_t)row * DIM + c * 4)
                                  : make_float4(0.f, 0.f, 0.f, 0.f);
        }
        const float xs = xsq[row];
        float bv = 3.4e38f; int bk = KCB;
        for (int wd = 0; wd < 8; wd++) {
            unsigned int m = mw[wd];
            while (m) {
                const int k = wd * 32 + __ffs(m) - 1;
                m &= m - 1;
                double a = 0.0;
                #pragma unroll
                for (int p = 0; p < 4; p++) {
                    const int c = lane + 64 * p;
                    if (c < DIM / 4) {
                        const float4 wq = *(const float4*)(w + (size_t)k * DIM + c * 4);
                        float pt = xq[p].x * wq.x;
                        pt = fmaf(xq[p].y, wq.y, pt);
                        pt = fmaf(xq[p].z, wq.z, pt);
                        pt = fmaf(xq[p].w, wq.w, pt);
                        a += (double)pt;
                    }
                }
                #pragma unroll
                for (int off = 32; off; off >>= 1) a += __shfl_xor(a, off, 64);
                const float c32 = (float)a;
                const float t1 = xs - 2.0f * c32;
                const float sv = t1 + wsq[k];
                if (sv < bv) { bv = sv; bk = k; }   // ascending k + strict < == lowest-index tiebreak
            }
        }
        const float4* src = (const float4*)(w + (size_t)bk * DIM);
        float4* dst = (float4*)(out + (size_t)row * DIM);
        for (int c = lane; c < DIM / 4; c += 64) dst[c] = src[c];
    }
}

extern "C" void kernel_launch(void* const* d_in, const int* in_sizes, int n_in,
                              void* d_out, int out_size, void* d_ws, size_t ws_size,
                              hipStream_t stream) {
    const float* x = (const float*)d_in[0];
    const float* w = (const float*)d_in[1];
    float* out  = (float*)d_out;
    float* base = (float*)d_ws;

    // workspace (words): wsq 256 | xsq 65536 | s1 65536 | counter 64 | rlist 65536
    //                  | cmask 524288 | whi 131072 | wlo 131072   = 983360 words
    const size_t NEED = 983360ull * 4ull;
    if (ws_size < NEED) {   // fallback: proven old path (needs only 257 KB)
        float* wsq = base;
        float* xsq = wsq + KCB;
        wsq_old_kernel<<<KCB / 4, 256, 0, stream>>>(w, wsq);
        xsq_old_kernel<<<N_ROWS / 4, 256, 0, stream>>>(x, xsq);
        vq_old_kernel<<<N_ROWS / RB, 256, 0, stream>>>(x, w, wsq, xsq, out);
        return;
    }

    float*          wsq     = base;                                  // 256
    float*          xsq     = base + 256;                            // 65536
    float*          s1      = base + 65792;                          // 65536
    unsigned int*   counter = (unsigned int*)(base + 131328);        // 64 (pad)
    unsigned int*   rlist   = (unsigned int*)(base + 131392);        // 65536
    unsigned int*   cmask   = (unsigned int*)(base + 196928);        // 524288
    unsigned short* whi     = (unsigned short*)(base + 721216);      // 131072 words
    unsigned short* wlo     = (unsigned short*)(base + 852288);      // 131072 words

    prep_kernel<<<KCB / 4, 256, 0, stream>>>(w, wsq, whi, wlo, counter);
    xsq_s1_kernel<<<N_ROWS / 4, 256, 0, stream>>>(x, xsq, s1);
    vq_main_kernel<<<N_ROWS / RBM, 256, 0, stream>>>(x, w, wsq, xsq, s1, whi, wlo,
                                                     cmask, rlist, counter, out);
    resolve_kernel<<<512, 256, 0, stream>>>(x, w, wsq, xsq, cmask, rlist, counter, out);
}

// Round 3
// 572.115 us; speedup vs baseline: 2.7791x; 1.0318x over previous
//
#include <hip/hip_runtime.h>
#include <stdint.h>

#define N_ROWS 65536
#define DIM    1000
#define KCB    256

// ---------------- old (proven) path: kept as fallback if ws_size is small ----------------
#define RB     64
#define DT     32
#define PITCH  36

__global__ __launch_bounds__(256) void wsq_old_kernel(const float* __restrict__ w,
                                                      float* __restrict__ wsq) {
    const int wave = threadIdx.x >> 6;
    const int lane = threadIdx.x & 63;
    const int k = blockIdx.x * 4 + wave;
    double s = 0.0;
    for (int c = lane; c < DIM / 4; c += 64) {
        const float4 v = *(const float4*)(w + k * DIM + c * 4);
        s += (double)v.x * v.x + (double)v.y * v.y + (double)v.z * v.z + (double)v.w * v.w;
    }
    #pragma unroll
    for (int off = 32; off; off >>= 1) s += __shfl_down(s, off, 64);
    if (lane == 0) wsq[k] = (float)s;
}

__global__ __launch_bounds__(256) void xsq_old_kernel(const float* __restrict__ x,
                                                      float* __restrict__ xsq) {
    const int wave = threadIdx.x >> 6;
    const int lane = threadIdx.x & 63;
    const int row = blockIdx.x * 4 + wave;
    double s = 0.0;
    for (int c = lane; c < DIM / 4; c += 64) {
        const float4 v = *(const float4*)(x + (size_t)row * DIM + c * 4);
        s += (double)v.x * v.x + (double)v.y * v.y + (double)v.z * v.z + (double)v.w * v.w;
    }
    #pragma unroll
    for (int off = 32; off; off >>= 1) s += __shfl_down(s, off, 64);
    if (lane == 0) xsq[row] = (float)s;
}

__global__ __launch_bounds__(256) void vq_old_kernel(const float* __restrict__ x,
                                                     const float* __restrict__ w,
                                                     const float* __restrict__ wsq,
                                                     const float* __restrict__ xsq,
                                                     float* __restrict__ out) {
    __shared__ float Xs[RB * PITCH];
    __shared__ float Ws[KCB * PITCH];
    __shared__ int   lidx[RB];

    const int tid  = threadIdx.x;
    const int row0 = blockIdx.x * RB;
    const int kt = tid & 31;
    const int rt = tid >> 5;

    double acc[8][8];
    #pragma unroll
    for (int i = 0; i < 8; i++)
        #pragma unroll
        for (int j = 0; j < 8; j++) acc[i][j] = 0.0;

    const int wk = tid >> 3;
    const int wg = tid & 7;
    const int xr = tid >> 2;
    const int xg = tid & 3;

    for (int d0 = 0; d0 < DIM; d0 += DT) {
        #pragma unroll
        for (int p = 0; p < 8; p++) {
            const int k = p * 32 + wk;
            const int d = d0 + wg * 4;
            float4 v = make_float4(0.f, 0.f, 0.f, 0.f);
            if (d < DIM) v = *(const float4*)(w + k * DIM + d);
            *(float4*)(&Ws[k * PITCH + wg * 4]) = v;
        }
        #pragma unroll
        for (int p = 0; p < 2; p++) {
            const int off = (xg + p * 4) * 4;
            const int d = d0 + off;
            float4 v = make_float4(0.f, 0.f, 0.f, 0.f);
            if (d < DIM) v = *(const float4*)(x + (size_t)(row0 + xr) * DIM + d);
            *(float4*)(&Xs[xr * PITCH + off]) = v;
        }
        __syncthreads();

        #pragma unroll
        for (int dq = 0; dq < DT; dq += 4) {
            float4 xf[8], wf[8];
            #pragma unroll
            for (int i = 0; i < 8; i++)
                xf[i] = *(const float4*)(&Xs[(rt + 8 * i) * PITCH + dq]);
            #pragma unroll
            for (int j = 0; j < 8; j++)
                wf[j] = *(const float4*)(&Ws[(kt + 32 * j) * PITCH + dq]);
            #pragma unroll
            for (int i = 0; i < 8; i++)
                #pragma unroll
                for (int j = 0; j < 8; j++) {
                    float p = xf[i].x * wf[j].x;
                    p = fmaf(xf[i].y, wf[j].y, p);
                    p = fmaf(xf[i].z, wf[j].z, p);
                    p = fmaf(xf[i].w, wf[j].w, p);
                    acc[i][j] += (double)p;
                }
        }
        __syncthreads();
    }

    #pragma unroll
    for (int i = 0; i < 8; i++) {
        const float xs = xsq[row0 + rt + 8 * i];
        float bestv = 3.4e38f;
        int   bestk = 0;
        #pragma unroll
        for (int j = 0; j < 8; j++) {
            const int k = kt + 32 * j;
            const float c32 = (float)acc[i][j];
            const float t1  = xs - 2.0f * c32;
            const float s   = t1 + wsq[k];
            if (s < bestv || (s == bestv && k < bestk)) { bestv = s; bestk = k; }
        }
        #pragma unroll
        for (int m = 16; m >= 1; m >>= 1) {
            const float ov = __shfl_xor(bestv, m, 64);
            const int   ok = __shfl_xor(bestk, m, 64);
            if (ov < bestv || (ov == bestv && ok < bestk)) { bestv = ov; bestk = ok; }
        }
        if (kt == 0) lidx[rt + 8 * i] = bestk;
    }
    __syncthreads();

    const int wave = tid >> 6;
    const int lane = tid & 63;
    for (int r = wave; r < RB; r += 4) {
        const int k = lidx[r];
        const float4* src = (const float4*)(w + k * DIM);
        float4* dst = (float4*)(out + (size_t)(row0 + r) * DIM);
        for (int c = lane; c < DIM / 4; c += 64) dst[c] = src[c];
    }
}

// ---------------- MFMA path ----------------
// cross(n,k) via 3 bf16 MFMA products in fp32 with SPLIT accumulators (margins as r2).
// Candidate mask per row in LDS; rows with >1 candidate are resolved IN-KERNEL with the
// exact fp64-quad pipeline (verbatim math/tie-break) before the gather. Output bit-identical.

#define RBM    64       // rows per block
#define NSTEP  32       // 1024 / 32 (D padded to 1024 with zeros)
#define XHI    0
#define XLO    4096
#define WHIO   8192
#define WLOO   24576
#define LDSB   40960    // bytes per buffer (X 8KB + W 32KB)

typedef short bf16x8 __attribute__((ext_vector_type(8)));
typedef float f32x4  __attribute__((ext_vector_type(4)));
typedef unsigned short us8 __attribute__((ext_vector_type(8)));

__device__ __forceinline__ unsigned short f2bf(float f) {  // RNE float->bf16
    union { float f; unsigned int u; } v; v.f = f;
    return (unsigned short)((v.u + 0x7FFFu + ((v.u >> 16) & 1u)) >> 16);
}
__device__ __forceinline__ float bf2f(unsigned short h) {
    union { float f; unsigned int u; } v; v.u = ((unsigned int)h) << 16;
    return v.f;
}
__device__ __forceinline__ void glds16(const void* g, void* l) {
    __builtin_amdgcn_global_load_lds((const __attribute__((address_space(1))) unsigned int*)g,
                                     (__attribute__((address_space(3))) unsigned int*)l, 16, 0, 0);
}

// wsq (bitwise-identical to old) + W split into fragment-arranged bf16 hi/lo arrays.
__global__ __launch_bounds__(256) void prep_kernel(const float* __restrict__ w,
        float* __restrict__ wsq, unsigned short* __restrict__ whi, unsigned short* __restrict__ wlo) {
    const int wave = threadIdx.x >> 6;
    const int lane = threadIdx.x & 63;
    const int k = blockIdx.x * 4 + wave;
    double s = 0.0;
    for (int c = lane; c < DIM / 4; c += 64) {
        const float4 v = *(const float4*)(w + k * DIM + c * 4);
        s += (double)v.x * v.x + (double)v.y * v.y + (double)v.z * v.z + (double)v.w * v.w;
    }
    #pragma unroll
    for (int off = 32; off; off >>= 1) s += __shfl_down(s, off, 64);
    if (lane == 0) wsq[k] = (float)s;

    const int ct = k >> 4, kl = k & 15;
    for (int c = lane; c < 256; c += 64) {           // 256 quads = 1024 padded dims
        float4 v = make_float4(0.f, 0.f, 0.f, 0.f);
        if (c < DIM / 4) v = *(const float4*)(w + k * DIM + c * 4);
        ushort4 h, l;
        h.x = f2bf(v.x); l.x = f2bf(v.x - bf2f(h.x));
        h.y = f2bf(v.y); l.y = f2bf(v.y - bf2f(h.y));
        h.z = f2bf(v.z); l.z = f2bf(v.z - bf2f(h.z));
        h.w = f2bf(v.w); l.w = f2bf(v.w - bf2f(h.w));
        const int step = c >> 3, qq = c & 7;
        const int pos = step * 16384 + ct * 1024 + ((qq >> 1) * 16 + kl) * 16 + (qq & 1) * 8;
        *(ushort4*)((char*)whi + pos) = h;
        *(ushort4*)((char*)wlo + pos) = l;
    }
}

// xsq bitwise-identical to old + S1 = sum|x| (fp64) for the margin bound.
__global__ __launch_bounds__(256) void xsq_s1_kernel(const float* __restrict__ x,
        float* __restrict__ xsq, float* __restrict__ s1) {
    const int wave = threadIdx.x >> 6;
    const int lane = threadIdx.x & 63;
    const int row = blockIdx.x * 4 + wave;
    double s = 0.0, a = 0.0;
    for (int c = lane; c < DIM / 4; c += 64) {
        const float4 v = *(const float4*)(x + (size_t)row * DIM + c * 4);
        s += (double)v.x * v.x + (double)v.y * v.y + (double)v.z * v.z + (double)v.w * v.w;
        a += (double)fabsf(v.x) + (double)fabsf(v.y) + (double)fabsf(v.z) + (double)fabsf(v.w);
    }
    #pragma unroll
    for (int off = 32; off; off >>= 1) { s += __shfl_down(s, off, 64); a += __shfl_down(a, off, 64); }
    if (lane == 0) { xsq[row] = (float)s; s1[row] = (float)a; }
}

__global__ __launch_bounds__(256, 2) void vq_main_kernel(
        const float* __restrict__ x, const float* __restrict__ w,
        const float* __restrict__ wsq, const float* __restrict__ xsq,
        const float* __restrict__ s1,
        const unsigned short* __restrict__ whi, const unsigned short* __restrict__ wlo,
        float* __restrict__ out) {
    __shared__ __align__(16) char lds[2 * LDSB];   // 80 KB -> 2 blocks/CU
    const int tid  = threadIdx.x;
    const int lane = tid & 63;
    const int wv   = tid >> 6;          // code group: codes [64*wv, 64*wv+64)
    const int row0 = blockIdx.x * RBM;

    // X staging (bank-conflict-free): lane l of wave wv writes LDS byte wv*1024 + l*16
    // (canonical contiguous). Thread -> row = 16*wv + (l&15), elems 8*qp..+7, qp=(l>>4)&3.
    const int qp   = (lane >> 4) & 3;
    const int srow = wv * 16 + (lane & 15);
    const size_t xrow_off = (size_t)(row0 + srow) * DIM;
    const int xpos0 = wv * 1024 + lane * 16;

    f32x4 accm[4][4], accc[4][4];
    {
        const f32x4 z = {0.f, 0.f, 0.f, 0.f};
        #pragma unroll
        for (int i = 0; i < 4; i++)
            #pragma unroll
            for (int j = 0; j < 4; j++) { accm[i][j] = z; accc[i][j] = z; }
    }

    // two named register sets (static indexing only - no runtime-indexed reg arrays)
    float4 xa0, xb0, xa1, xb1;
    auto xloadA = [&](int t) {
        const int dA = t * 32 + qp * 8, dB = dA + 4;
        xa0 = (dA <= DIM - 4) ? *(const float4*)(x + xrow_off + dA) : make_float4(0.f, 0.f, 0.f, 0.f);
        xb0 = (dB <= DIM - 4) ? *(const float4*)(x + xrow_off + dB) : make_float4(0.f, 0.f, 0.f, 0.f);
    };
    auto xloadB = [&](int t) {
        const int dA = t * 32 + qp * 8, dB = dA + 4;
        xa1 = (dA <= DIM - 4) ? *(const float4*)(x + xrow_off + dA) : make_float4(0.f, 0.f, 0.f, 0.f);
        xb1 = (dB <= DIM - 4) ? *(const float4*)(x + xrow_off + dB) : make_float4(0.f, 0.f, 0.f, 0.f);
    };
    auto xstore = [&](int b, const float4& xa, const float4& xb) {
        us8 h, l;
        h[0] = f2bf(xa.x); l[0] = f2bf(xa.x - bf2f(h[0]));
        h[1] = f2bf(xa.y); l[1] = f2bf(xa.y - bf2f(h[1]));
        h[2] = f2bf(xa.z); l[2] = f2bf(xa.z - bf2f(h[2]));
        h[3] = f2bf(xa.w); l[3] = f2bf(xa.w - bf2f(h[3]));
        h[4] = f2bf(xb.x); l[4] = f2bf(xb.x - bf2f(h[4]));
        h[5] = f2bf(xb.y); l[5] = f2bf(xb.y - bf2f(h[5]));
        h[6] = f2bf(xb.z); l[6] = f2bf(xb.z - bf2f(h[6]));
        h[7] = f2bf(xb.w); l[7] = f2bf(xb.w - bf2f(h[7]));
        *(us8*)(lds + b * LDSB + XHI + xpos0) = h;
        *(us8*)(lds + b * LDSB + XLO + xpos0) = l;
    };
    auto wstage = [&](int b, int t) {
        #pragma unroll
        for (int i = 0; i < 4; i++) {
            const int ch = wv * 4 + i;
            glds16(whi + (size_t)t * 8192 + ch * 512 + lane * 8, lds + b * LDSB + WHIO + ch * 1024);
            glds16(wlo + (size_t)t * 8192 + ch * 512 + lane * 8, lds + b * LDSB + WLOO + ch * 1024);
        }
    };
    auto compute = [&](int b) {
        const char* base = lds + b * LDSB;
        bf16x8 ahi[4], alo[4];
        #pragma unroll
        for (int rt = 0; rt < 4; rt++) {
            ahi[rt] = *(const bf16x8*)(base + XHI + rt * 1024 + lane * 16);
            alo[rt] = *(const bf16x8*)(base + XLO + rt * 1024 + lane * 16);
        }
        __builtin_amdgcn_s_setprio(1);
        #pragma unroll
        for (int jt = 0; jt < 4; jt++) {
            const int ct = wv * 4 + jt;
            const bf16x8 bhi = *(const bf16x8*)(base + WHIO + ct * 1024 + lane * 16);
            const bf16x8 blo = *(const bf16x8*)(base + WLOO + ct * 1024 + lane * 16);
            #pragma unroll
            for (int rt = 0; rt < 4; rt++) {
                accm[rt][jt] = __builtin_amdgcn_mfma_f32_16x16x32_bf16(ahi[rt], bhi, accm[rt][jt], 0, 0, 0);
                accc[rt][jt] = __builtin_amdgcn_mfma_f32_16x16x32_bf16(ahi[rt], blo, accc[rt][jt], 0, 0, 0);
                accc[rt][jt] = __builtin_amdgcn_mfma_f32_16x16x32_bf16(alo[rt], bhi, accc[rt][jt], 0, 0, 0);
            }
        }
        __builtin_amdgcn_s_setprio(0);
    };

    // prologue: data0 -> buf0; data1 -> regs(B); W tile0 staged
    wstage(0, 0);
    xloadA(0); xstore(0, xa0, xb0);
    xloadB(1);
    __syncthreads();

    // main loop, unrolled x2 (even t: prev=setB, next=setA; odd t: prev=setA, next=setB)
    for (int t = 0; t < 30; t += 2) {
        // even step t: reads buf(t&1)=0-parity, writes data(t+1) to other buf
        xloadA(t + 2);
        xstore(1 - (t & 1), xa1, xb1);
        wstage(1 - (t & 1), t + 1);
        compute(t & 1);
        __syncthreads();
        // odd step t+1
        xloadB(t + 3);
        xstore(t & 1, xa0, xb0);
        wstage(t & 1, t + 2);
        compute(1 - (t & 1));
        __syncthreads();
    }
    // t = 30 (even, prev=setB holds data31)
    xstore(1, xa1, xb1);
    wstage(1, 31);
    compute(0);
    __syncthreads();
    // t = 31
    compute(1);
    __syncthreads();

    // merge split accumulators: c_hat = acc_m + acc_c
    #pragma unroll
    for (int i = 0; i < 4; i++)
        #pragma unroll
        for (int j = 0; j < 4; j++) accm[i][j] += accc[i][j];

    // ---- epilogue: shat, per-row min, margin mask ----
    const int g  = lane >> 4;
    const int cl = lane & 15;
    float* minw = (float*)lds;                           // [64][4]   bytes [0,1024)
    unsigned short* m16 = (unsigned short*)(lds + 1024); // [64][16]  bytes [1024,3072)
    int* lidx   = (int*)(lds + 3072);                    // [64]      bytes [3072,3328)
    int* mlist  = (int*)(lds + 3328);                    // [64]      bytes [3328,3584)
    int* nmulti = (int*)(lds + 3584);                    // [1]

    float wsqv[4];
    #pragma unroll
    for (int jt = 0; jt < 4; jt++) wsqv[jt] = wsq[wv * 64 + jt * 16 + cl];

    float xsv[4][4], mv[4][4];
    #pragma unroll
    for (int rt = 0; rt < 4; rt++)
        #pragma unroll
        for (int e = 0; e < 4; e++) {
            const int r = row0 + rt * 16 + g * 4 + e;
            const float xs = xsq[r];
            xsv[rt][e] = xs;
            mv[rt][e] = 2.5e-6f * s1[r] + 6e-7f * (xs + 64.0f) + 1e-12f;
        }

    #pragma unroll
    for (int rt = 0; rt < 4; rt++)
        #pragma unroll
        for (int jt = 0; jt < 4; jt++)
            #pragma unroll
            for (int e = 0; e < 4; e++) {
                const float c = accm[rt][jt][e];
                const float t1 = xsv[rt][e] - 2.0f * c;
                accm[rt][jt][e] = t1 + wsqv[jt];      // shat, same rounding pipeline as exact path
            }

    #pragma unroll
    for (int rt = 0; rt < 4; rt++)
        #pragma unroll
        for (int e = 0; e < 4; e++) {
            float mn = fminf(fminf(accm[rt][0][e], accm[rt][1][e]), fminf(accm[rt][2][e], accm[rt][3][e]));
            #pragma unroll
            for (int m = 8; m; m >>= 1) mn = fminf(mn, __shfl_xor(mn, m, 64));
            if (cl == 0) minw[(rt * 16 + g * 4 + e) * 4 + wv] = mn;
        }
    __syncthreads();

    float tv[4][4];
    #pragma unroll
    for (int rt = 0; rt < 4; rt++)
        #pragma unroll
        for (int e = 0; e < 4; e++) {
            const int r = rt * 16 + g * 4 + e;
            const float gm = fminf(fminf(minw[r * 4 + 0], minw[r * 4 + 1]),
                                   fminf(minw[r * 4 + 2], minw[r * 4 + 3]));
            tv[rt][e] = gm + mv[rt][e];
        }
    #pragma unroll
    for (int rt = 0; rt < 4; rt++)
        #pragma unroll
        for (int jt = 0; jt < 4; jt++)
            #pragma unroll
            for (int e = 0; e < 4; e++) {
                const unsigned long long b = __ballot(accm[rt][jt][e] <= tv[rt][e]);
                if (cl == 0)
                    m16[(rt * 16 + g * 4 + e) * 16 + wv * 4 + jt] = (unsigned short)(b >> (g * 16));
            }
    __syncthreads();

    // wave 0: provisional argmin (lowest candidate) + compact multi-candidate row list
    if (wv == 0) {
        unsigned int mw[8];
        int cnt = 0;
        #pragma unroll
        for (int i = 0; i < 8; i++) {
            mw[i] = (unsigned int)m16[lane * 16 + 2 * i] | ((unsigned int)m16[lane * 16 + 2 * i + 1] << 16);
            cnt += __popc(mw[i]);
        }
        int kb = 0;
        #pragma unroll
        for (int i = 7; i >= 0; i--) if (mw[i]) kb = 32 * i + __ffs(mw[i]) - 1;   // lowest set bit
        lidx[lane] = kb;
        const unsigned long long act = __ballot(cnt > 1);
        if (cnt > 1) {
            const int pfx = __popcll(act & ((1ull << lane) - 1ull));
            mlist[pfx] = lane;
        }
        if (lane == 0) nmulti[0] = __popcll(act);
    }
    __syncthreads();

    // in-kernel exact resolve (fp64-quad pipeline, verbatim order + tie-break)
    const int nm = nmulti[0];
    for (int i = wv; i < nm; i += 4) {
        const int r = mlist[i];
        unsigned int mw[8];
        #pragma unroll
        for (int q = 0; q < 8; q++)
            mw[q] = (unsigned int)m16[r * 16 + 2 * q] | ((unsigned int)m16[r * 16 + 2 * q + 1] << 16);

        float4 xq[4];
        #pragma unroll
        for (int p = 0; p < 4; p++) {
            const int c = lane + 64 * p;
            xq[p] = (c < DIM / 4) ? *(const float4*)(x + (size_t)(row0 + r) * DIM + c * 4)
                                  : make_float4(0.f, 0.f, 0.f, 0.f);
        }
        const float xs = xsq[row0 + r];
        float bv = 3.4e38f; int bk = KCB;
        for (int wd = 0; wd < 8; wd++) {
            unsigned int m = mw[wd];
            while (m) {
                const int k = wd * 32 + __ffs(m) - 1;
                m &= m - 1;
                double a = 0.0;
                #pragma unroll
                for (int p = 0; p < 4; p++) {
                    const int c = lane + 64 * p;
                    if (c < DIM / 4) {
                        const float4 wq = *(const float4*)(w + (size_t)k * DIM + c * 4);
                        float pt = xq[p].x * wq.x;
                        pt = fmaf(xq[p].y, wq.y, pt);
                        pt = fmaf(xq[p].z, wq.z, pt);
                        pt = fmaf(xq[p].w, wq.w, pt);
                        a += (double)pt;
                    }
                }
                #pragma unroll
                for (int off = 32; off; off >>= 1) a += __shfl_xor(a, off, 64);
                const float c32 = (float)a;
                const float t1 = xs - 2.0f * c32;
                const float sv = t1 + wsq[k];
                if (sv < bv) { bv = sv; bk = k; }   // ascending k + strict < == lowest-index tiebreak
            }
        }
        if (lane == 0) lidx[r] = bk;
    }
    __syncthreads();

    // gather
    for (int r = wv; r < RBM; r += 4) {
        const int k = lidx[r];
        const float4* src = (const float4*)(w + (size_t)k * DIM);
        float4* dst = (float4*)(out + (size_t)(row0 + r) * DIM);
        for (int c = lane; c < DIM / 4; c += 64) dst[c] = src[c];
    }
}

extern "C" void kernel_launch(void* const* d_in, const int* in_sizes, int n_in,
                              void* d_out, int out_size, void* d_ws, size_t ws_size,
                              hipStream_t stream) {
    const float* x = (const float*)d_in[0];
    const float* w = (const float*)d_in[1];
    float* out  = (float*)d_out;
    float* base = (float*)d_ws;

    // workspace (words): wsq 256 | xsq 65536 | s1 65536 | whi 131072 | wlo 131072 = 393472
    const size_t NEED = 393472ull * 4ull;
    if (ws_size < NEED) {   // fallback: proven old path (needs only 257 KB)
        float* wsq = base;
        float* xsq = wsq + KCB;
        wsq_old_kernel<<<KCB / 4, 256, 0, stream>>>(w, wsq);
        xsq_old_kernel<<<N_ROWS / 4, 256, 0, stream>>>(x, xsq);
        vq_old_kernel<<<N_ROWS / RB, 256, 0, stream>>>(x, w, wsq, xsq, out);
        return;
    }

    float*          wsq = base;                                  // 256
    float*          xsq = base + 256;                            // 65536
    float*          s1  = base + 65792;                          // 65536
    unsigned short* whi = (unsigned short*)(base + 131328);      // 131072 words
    unsigned short* wlo = (unsigned short*)(base + 262400);      // 131072 words

    prep_kernel<<<KCB / 4, 256, 0, stream>>>(w, wsq, whi, wlo);
    xsq_s1_kernel<<<N_ROWS / 4, 256, 0, stream>>>(x, xsq, s1);
    vq_main_kernel<<<N_ROWS / RBM, 256, 0, stream>>>(x, w, wsq, xsq, s1, whi, wlo, out);
}